// Round 1
// baseline (701.562 us; speedup 1.0000x reference)
//
#include <hip/hip_runtime.h>
#include <string.h>

#define H 128
#define NTYPES 28
#define CNT_BYTES_PER_CYCLE 32   // 28 byte counters + 4 pad, dword-packed

// ---- binned-histogram count path ----
// bucket = cycle >> BKT_SHIFT (512 cycles/bucket). Mean load 2M/977 = 2048,
// sigma ~45; CAP=3072 is +22 sigma. Overflow goes to an exact side list.
#define BKT_SHIFT 9
#define BKT_CYCLES (1 << BKT_SHIFT)
#define BKT_CAP 3072

// ws header layout (memset'd to 0 each launch, 8 KB total)
#define OFF_BINCNT 0      // nb * 4 bytes (nb <= 1024 guarded)
#define OFF_OVFCNT 4096   // 4 bytes
#define OFF_BINS   8192

__device__ __forceinline__ void push_key(unsigned key,
                                         unsigned* __restrict__ bins,
                                         unsigned* __restrict__ bincnt,
                                         unsigned* __restrict__ ovf,
                                         unsigned* __restrict__ ovfcnt) {
    unsigned b = key >> (5 + BKT_SHIFT);              // = cycle >> BKT_SHIFT
    unsigned pos = atomicAdd(&bincnt[b], 1u);
    if (pos < BKT_CAP) bins[(size_t)b * BKT_CAP + pos] = key;
    else               ovf[atomicAdd(ovfcnt, 1u)] = key;   // ovf sized n_inc: never OOB
}

// K1: incidences -> bucketed key lists. 4 per thread, int4 loads.
// Atomics hit only ~977 hot counters (fast same-address path); data writes
// land on ~977 active frontier lines instead of 2M random line-RMWs.
__global__ void scatter_bin_kernel(const int* __restrict__ a2c,
                                   const int* __restrict__ x,
                                   unsigned* __restrict__ bins,
                                   unsigned* __restrict__ bincnt,
                                   unsigned* __restrict__ ovf,
                                   unsigned* __restrict__ ovfcnt,
                                   int n_inc) {
    int i = (blockIdx.x * blockDim.x + threadIdx.x) * 4;
    if (i + 3 < n_inc) {
        int4 at = *(const int4*)(a2c + i);
        int4 cy = *(const int4*)(a2c + n_inc + i);
        int t0 = x[at.x], t1 = x[at.y], t2 = x[at.z], t3 = x[at.w];
        push_key(((unsigned)cy.x << 5) | (unsigned)t0, bins, bincnt, ovf, ovfcnt);
        push_key(((unsigned)cy.y << 5) | (unsigned)t1, bins, bincnt, ovf, ovfcnt);
        push_key(((unsigned)cy.z << 5) | (unsigned)t2, bins, bincnt, ovf, ovfcnt);
        push_key(((unsigned)cy.w << 5) | (unsigned)t3, bins, bincnt, ovf, ovfcnt);
    } else {
        for (int e = i; e < n_inc; ++e) {
            unsigned key = ((unsigned)a2c[n_inc + e] << 5) | (unsigned)x[a2c[e]];
            push_key(key, bins, bincnt, ovf, ovfcnt);
        }
    }
}

// K2: one block per bucket. LDS byte-packed counters (16 KB), ds_add per key,
// dense coalesced cnt write. Replaces 2M scattered global atomic RMWs with
// 2M LDS atomics + 16 MB streaming write; also removes the 16 MB cnt memset.
__global__ __launch_bounds__(256) void bucket_hist_kernel(
        const unsigned* __restrict__ bins,
        const unsigned* __restrict__ bincnt,
        unsigned* __restrict__ cnt,
        int num_cycles) {
    __shared__ unsigned h[BKT_CYCLES * 8];            // 512 cycles * 32 B = 16 KB
    int b = blockIdx.x;
    for (int j = threadIdx.x; j < BKT_CYCLES * 8; j += blockDim.x) h[j] = 0;
    __syncthreads();
    unsigned n = bincnt[b];
    if (n > BKT_CAP) n = BKT_CAP;                     // excess went to ovf list
    const unsigned* mybin = bins + (size_t)b * BKT_CAP;
    for (unsigned k = threadIdx.x; k < n; k += blockDim.x) {
        unsigned key   = mybin[k];
        unsigned local = (key >> 5) & (BKT_CYCLES - 1);
        unsigned t     = key & 31u;
        atomicAdd(&h[local * 8 + (t >> 2)], 1u << (8 * (t & 3)));   // ds_add_u32
    }
    __syncthreads();
    int base_dw = b * BKT_CYCLES * 8;
    int ndw = BKT_CYCLES * 8;
    int lim = num_cycles * 8 - base_dw;               // partial last bucket
    if (lim < ndw) ndw = lim;
    for (int j = threadIdx.x; j < ndw; j += blockDim.x)
        cnt[(size_t)base_dw + j] = h[j];
}

// K3: apply overflow keys (expected count: 0) exactly.
__global__ void ovf_apply_kernel(const unsigned* __restrict__ ovf,
                                 const unsigned* __restrict__ ovfcnt,
                                 unsigned* __restrict__ cnt) {
    unsigned n = *ovfcnt;
    for (unsigned k = blockIdx.x * blockDim.x + threadIdx.x; k < n;
         k += gridDim.x * blockDim.x) {
        unsigned key = ovf[k];
        unsigned cy = key >> 5, t = key & 31u;
        atomicAdd(&cnt[(size_t)cy * 8 + (t >> 2)], 1u << (8 * (t & 3)));
    }
}

// ---- legacy count (fallback when ws fits cnt only) ----
__global__ void count_kernel(const int* __restrict__ a2c,
                             const int* __restrict__ x,
                             unsigned* __restrict__ cnt,
                             int n_inc) {
    int i = (blockIdx.x * blockDim.x + threadIdx.x) * 4;
    if (i + 3 < n_inc) {
        int4 at = *(const int4*)(a2c + i);
        int4 cy = *(const int4*)(a2c + n_inc + i);
        int t0 = x[at.x], t1 = x[at.y], t2 = x[at.z], t3 = x[at.w];
        atomicAdd(&cnt[cy.x * 8 + (t0 >> 2)], 1u << (8 * (t0 & 3)));
        atomicAdd(&cnt[cy.y * 8 + (t1 >> 2)], 1u << (8 * (t1 & 3)));
        atomicAdd(&cnt[cy.z * 8 + (t2 >> 2)], 1u << (8 * (t2 & 3)));
        atomicAdd(&cnt[cy.w * 8 + (t3 >> 2)], 1u << (8 * (t3 & 3)));
    } else {
        for (int e = i; e < n_inc; ++e) {
            int atom = a2c[e];
            int cycv = a2c[n_inc + e];
            int t = x[atom];
            atomicAdd(&cnt[cycv * 8 + (t >> 2)], 1u << (8 * (t & 3)));
        }
    }
}

// ---- expand: one wave per cycle (grid-stride): out[c] = sum_t cnt[c][t]*emb[t] ----
// (unchanged this round: modeled at ~50-60 us, near its 256 MB NT-store floor)
__global__ __launch_bounds__(256) void expand_kernel(
        const unsigned char* __restrict__ cnt,
        const float* __restrict__ emb,
        float* __restrict__ out,
        int num_cycles) {
    __shared__ __align__(16) float lds[NTYPES * H];
    for (int i = threadIdx.x; i < NTYPES * H; i += blockDim.x) lds[i] = emb[i];
    __syncthreads();
    const float2* l2 = (const float2*)lds;

    int lane = threadIdx.x & 63;
    int w    = blockIdx.x * (blockDim.x >> 6) + (threadIdx.x >> 6);
    int nw   = gridDim.x * (blockDim.x >> 6);

    for (int c = w; c < num_cycles; c += nw) {
        unsigned b = cnt[(size_t)c * CNT_BYTES_PER_CYCLE + (lane & 31)];
        unsigned long long m = __ballot(b != 0) & 0x0FFFFFFFull;
        float2 acc = {0.f, 0.f};
        while (m) {
            int t = __builtin_ctzll(m);
            m &= m - 1;
            float f = (float)__builtin_amdgcn_readlane((int)b, t);
            float2 wv = l2[t * 64 + lane];
            acc.x += f * wv.x;
            acc.y += f * wv.y;
        }
        unsigned long long bits;
        memcpy(&bits, &acc, 8);
        __builtin_nontemporal_store(
            bits, (unsigned long long*)(out + (size_t)c * H) + lane);
    }
}

// ---- fallback (ws too small): direct atomic scatter ----
__global__ void scatter_direct_kernel(const int* __restrict__ a2c,
                                      const int* __restrict__ x,
                                      const float* __restrict__ emb,
                                      float* __restrict__ out,
                                      int n_inc) {
    int gid = blockIdx.x * blockDim.x + threadIdx.x;
    int e  = gid >> 5;
    int ch = gid & 31;
    if (e >= n_inc) return;
    int atom = a2c[e];
    int cyc  = a2c[n_inc + e];
    int t    = x[atom];
    const float4 w = ((const float4*)(emb + t * H))[ch];
    float* o = out + (size_t)cyc * H + ch * 4;
    atomicAdd(o + 0, w.x);
    atomicAdd(o + 1, w.y);
    atomicAdd(o + 2, w.z);
    atomicAdd(o + 3, w.w);
}

__global__ void zero_u4_kernel(uint4* __restrict__ p, int n4) {
    int i = blockIdx.x * blockDim.x + threadIdx.x;
    if (i < n4) p[i] = make_uint4(0u, 0u, 0u, 0u);
}

extern "C" void kernel_launch(void* const* d_in, const int* in_sizes, int n_in,
                              void* d_out, int out_size, void* d_ws, size_t ws_size,
                              hipStream_t stream) {
    const int*   x    = (const int*)d_in[0];
    const int*   a2c  = (const int*)d_in[1];
    const float* emb  = (const float*)d_in[2];
    float*       out  = (float*)d_out;

    const int n_inc      = in_sizes[1] / 2;
    const int num_cycles = out_size / H;
    const size_t cnt_bytes = (size_t)num_cycles * CNT_BYTES_PER_CYCLE;

    const int    nb         = (num_cycles + BKT_CYCLES - 1) >> BKT_SHIFT;
    const size_t bins_bytes = (size_t)nb * BKT_CAP * 4;
    const size_t ovf_bytes  = (size_t)n_inc * 4;
    const size_t off_ovf    = OFF_BINS + bins_bytes;
    const size_t off_cnt    = (off_ovf + ovf_bytes + 255) & ~(size_t)255;
    const size_t need       = off_cnt + cnt_bytes;

    if (ws_size >= need && (size_t)nb * 4 <= OFF_OVFCNT) {
        char* w = (char*)d_ws;
        unsigned* bincnt = (unsigned*)(w + OFF_BINCNT);
        unsigned* ovfcnt = (unsigned*)(w + OFF_OVFCNT);
        unsigned* bins   = (unsigned*)(w + OFF_BINS);
        unsigned* ovf    = (unsigned*)(w + off_ovf);
        unsigned* cnt    = (unsigned*)(w + off_cnt);

        hipMemsetAsync(w, 0, OFF_BINS, stream);   // 8 KB header only (no 16 MB memset)
        int nthreads = (n_inc + 3) / 4;
        scatter_bin_kernel<<<(nthreads + 255) / 256, 256, 0, stream>>>(
            a2c, x, bins, bincnt, ovf, ovfcnt, n_inc);
        bucket_hist_kernel<<<nb, 256, 0, stream>>>(bins, bincnt, cnt, num_cycles);
        ovf_apply_kernel<<<256, 256, 0, stream>>>(ovf, ovfcnt, cnt);
        expand_kernel<<<2048, 256, 0, stream>>>(
            (const unsigned char*)cnt, emb, out, num_cycles);
    } else if (ws_size >= cnt_bytes) {
        unsigned* cnt = (unsigned*)d_ws;
        hipMemsetAsync(d_ws, 0, cnt_bytes, stream);
        int nthreads = (n_inc + 3) / 4;
        count_kernel<<<(nthreads + 255) / 256, 256, 0, stream>>>(a2c, x, cnt, n_inc);
        expand_kernel<<<2048, 256, 0, stream>>>(
            (const unsigned char*)cnt, emb, out, num_cycles);
    } else {
        int n4 = out_size / 4;
        zero_u4_kernel<<<(n4 + 255) / 256, 256, 0, stream>>>((uint4*)d_out, n4);
        long long total = (long long)n_inc * 32;
        int blocks = (int)((total + 255) / 256);
        scatter_direct_kernel<<<blocks, 256, 0, stream>>>(a2c, x, emb, out, n_inc);
    }
}

// Round 2
// 365.446 us; speedup vs baseline: 1.9197x; 1.9197x over previous
//
#include <hip/hip_runtime.h>
#include <string.h>

#define H 128
#define NTYPES 28
#define CNT_BYTES_PER_CYCLE 32   // 28 byte counters + 4 pad, dword-packed

typedef float f32x4 __attribute__((ext_vector_type(4)));

// ---- count: one incidence -> +1 on byte counter cnt[cycle][type] ----
// 4 incidences per thread, int4 loads on both index rows. Fire-and-forget
// 32-bit atomics (no return value -> no serialization chain); ~85 us at the
// device scattered-atomic rate. (Binned/position-atomic variant measured
// 416 us in R1 -- returning atomics on ~1K hot addresses serialize.)
__global__ void count_kernel(const int* __restrict__ a2c,
                             const int* __restrict__ x,
                             unsigned* __restrict__ cnt,
                             int n_inc) {
    int i = (blockIdx.x * blockDim.x + threadIdx.x) * 4;
    if (i + 3 < n_inc) {
        int4 at = *(const int4*)(a2c + i);
        int4 cy = *(const int4*)(a2c + n_inc + i);
        int t0 = x[at.x], t1 = x[at.y], t2 = x[at.z], t3 = x[at.w];
        atomicAdd(&cnt[cy.x * 8 + (t0 >> 2)], 1u << (8 * (t0 & 3)));
        atomicAdd(&cnt[cy.y * 8 + (t1 >> 2)], 1u << (8 * (t1 & 3)));
        atomicAdd(&cnt[cy.z * 8 + (t2 >> 2)], 1u << (8 * (t2 & 3)));
        atomicAdd(&cnt[cy.w * 8 + (t3 >> 2)], 1u << (8 * (t3 & 3)));
    } else {
        for (int e = i; e < n_inc; ++e) {
            int atom = a2c[e];
            int cycv = a2c[n_inc + e];
            int t = x[atom];
            atomicAdd(&cnt[cycv * 8 + (t >> 2)], 1u << (8 * (t & 3)));
        }
    }
}

// ---- expand2: one wave per PAIR of cycles, contiguous chunks ----
// lanes 0-31 -> cycle 2p, lanes 32-63 -> cycle 2p+1.
// Per iteration: one coalesced 64 B cnt read (vs 32 B re-read before), one
// contiguous 1 KB NT store (vs 512 B), depth-2 prefetch kills the
// load->ballot serial chain, float4 ds_read_b128 + FMA.
// Per-half masks from one 64-bit ballot; count byte pulled via ds_bpermute
// (__shfl with VGPR lane index t + half*32).
__global__ __launch_bounds__(256) void expand2_kernel(
        const unsigned char* __restrict__ cnt,
        const float* __restrict__ emb,
        float* __restrict__ out,
        int num_cycles) {
    __shared__ __align__(16) float lds[NTYPES * H];
    for (int i = threadIdx.x; i < NTYPES * H; i += blockDim.x) lds[i] = emb[i];
    __syncthreads();
    const f32x4* l4 = (const f32x4*)lds;

    const int lane = threadIdx.x & 63;
    const int half = lane >> 5;
    const int hl   = lane & 31;
    const int w    = blockIdx.x * (blockDim.x >> 6) + (threadIdx.x >> 6);
    const int nw   = gridDim.x * (blockDim.x >> 6);

    const int P   = (num_cycles + 1) >> 1;        // cycle pairs
    const int ppw = (P + nw - 1) / nw;            // pairs per wave (contiguous)
    int p0 = w * ppw;
    int p1 = p0 + ppw; if (p1 > P) p1 = P;
    if (p0 >= p1) return;

    // depth-2 prefetch of the 64 B counter line (1 byte/lane)
    unsigned b0 = cnt[(size_t)p0 * 64 + lane];
    unsigned b1 = (p0 + 1 < p1) ? cnt[(size_t)(p0 + 1) * 64 + lane] : 0u;

    for (int p = p0; p < p1; ++p) {
        unsigned b = b0;
        b0 = b1;
        b1 = (p + 2 < p1) ? cnt[(size_t)(p + 2) * 64 + lane] : 0u;

        int c = 2 * p + half;
        unsigned long long bal = __ballot(b != 0);
        unsigned m = (half ? (unsigned)(bal >> 32) : (unsigned)bal) & 0x0FFFFFFFu;
        if (c >= num_cycles) m = 0;               // odd-tail guard (garbage half)

        f32x4 acc = {0.f, 0.f, 0.f, 0.f};
        while (m) {                               // iters = max(pop(m0),pop(m1)) ~ 5
            int t = __builtin_ctz(m);
            m &= m - 1;
            float f = (float)(unsigned)__shfl((int)b, t + (half << 5));
            f32x4 wv = l4[t * 32 + hl];           // ds_read_b128, conflict-free
            acc += f * wv;
        }
        if (c < num_cycles) {
            f32x4* dst = (f32x4*)(out + (size_t)c * H) + hl;
            __builtin_nontemporal_store(acc, dst);
        }
    }
}

// ---- fallback (ws too small): direct atomic scatter ----
__global__ void scatter_direct_kernel(const int* __restrict__ a2c,
                                      const int* __restrict__ x,
                                      const float* __restrict__ emb,
                                      float* __restrict__ out,
                                      int n_inc) {
    int gid = blockIdx.x * blockDim.x + threadIdx.x;
    int e  = gid >> 5;
    int ch = gid & 31;
    if (e >= n_inc) return;
    int atom = a2c[e];
    int cyc  = a2c[n_inc + e];
    int t    = x[atom];
    const float4 w = ((const float4*)(emb + t * H))[ch];
    float* o = out + (size_t)cyc * H + ch * 4;
    atomicAdd(o + 0, w.x);
    atomicAdd(o + 1, w.y);
    atomicAdd(o + 2, w.z);
    atomicAdd(o + 3, w.w);
}

__global__ void zero_u4_kernel(uint4* __restrict__ p, int n4) {
    int i = blockIdx.x * blockDim.x + threadIdx.x;
    if (i < n4) p[i] = make_uint4(0u, 0u, 0u, 0u);
}

extern "C" void kernel_launch(void* const* d_in, const int* in_sizes, int n_in,
                              void* d_out, int out_size, void* d_ws, size_t ws_size,
                              hipStream_t stream) {
    const int*   x    = (const int*)d_in[0];
    const int*   a2c  = (const int*)d_in[1];
    const float* emb  = (const float*)d_in[2];
    float*       out  = (float*)d_out;

    const int n_inc      = in_sizes[1] / 2;
    const int num_cycles = out_size / H;
    const size_t cnt_bytes = (size_t)num_cycles * CNT_BYTES_PER_CYCLE;

    if (ws_size >= cnt_bytes) {
        unsigned* cnt = (unsigned*)d_ws;
        hipMemsetAsync(d_ws, 0, cnt_bytes, stream);
        int nthreads = (n_inc + 3) / 4;
        count_kernel<<<(nthreads + 255) / 256, 256, 0, stream>>>(a2c, x, cnt, n_inc);
        // 2048 blocks x 256 threads = 8192 waves: full residency at 32 waves/CU
        expand2_kernel<<<2048, 256, 0, stream>>>(
            (const unsigned char*)cnt, emb, out, num_cycles);
    } else {
        int n4 = out_size / 4;
        zero_u4_kernel<<<(n4 + 255) / 256, 256, 0, stream>>>((uint4*)d_out, n4);
        long long total = (long long)n_inc * 32;
        int blocks = (int)((total + 255) / 256);
        scatter_direct_kernel<<<blocks, 256, 0, stream>>>(a2c, x, emb, out, n_inc);
    }
}